// Round 2
// baseline (819.657 us; speedup 1.0000x reference)
//
#include <hip/hip_runtime.h>
#include <math.h>

typedef _Float16 f16x8 __attribute__((ext_vector_type(8)));
typedef float    f32x4 __attribute__((ext_vector_type(4)));

#define SEQ   2048
#define DH    64
#define BM    64            // q-rows per block in pass 2 (4 waves x 16 rows)
#define BK    64            // k-chunk per iteration
#define PITCH 72            // halves per LDS row: 64 + 8 pad -> bank rotate 4
#define LOG2E 1.44269504088896340736f

// ================= Pass 1: per-row softmax stats (max m, sum-of-exp l) ===========
// One wave per row. Row (2048 floats) held in 32 regs; one streaming read only.
// Stats stored into out[row][0] = m, out[row][1] = l  (pass 2 reads then overwrites).
extern "C" __global__ __launch_bounds__(256, 8)
void softmax_stats(const float* __restrict__ x1, float* __restrict__ out)
{
    const int tid  = threadIdx.x;
    const int wave = tid >> 6;
    const int lane = tid & 63;
    const size_t row = (size_t)blockIdx.x * 4 + wave;     // over bh*SEQ rows
    const float* rp = x1 + row * SEQ + lane * 4;

    float4 v[8];
#pragma unroll
    for (int i = 0; i < 8; ++i) v[i] = *(const float4*)(rp + i * 256);

    float4 m4 = v[0];
#pragma unroll
    for (int i = 1; i < 8; ++i) {
        m4.x = fmaxf(m4.x, v[i].x); m4.y = fmaxf(m4.y, v[i].y);
        m4.z = fmaxf(m4.z, v[i].z); m4.w = fmaxf(m4.w, v[i].w);
    }
    float m = fmaxf(fmaxf(m4.x, m4.y), fmaxf(m4.z, m4.w));
#pragma unroll
    for (int s = 1; s < 64; s <<= 1) m = fmaxf(m, __shfl_xor(m, s));

    const float sh = m * LOG2E;
    float4 s4 = {0.f, 0.f, 0.f, 0.f};
#pragma unroll
    for (int i = 0; i < 8; ++i) {
        s4.x += __builtin_amdgcn_exp2f(__builtin_fmaf(v[i].x, LOG2E, -sh));
        s4.y += __builtin_amdgcn_exp2f(__builtin_fmaf(v[i].y, LOG2E, -sh));
        s4.z += __builtin_amdgcn_exp2f(__builtin_fmaf(v[i].z, LOG2E, -sh));
        s4.w += __builtin_amdgcn_exp2f(__builtin_fmaf(v[i].w, LOG2E, -sh));
    }
    float l = (s4.x + s4.y) + (s4.z + s4.w);
#pragma unroll
    for (int s = 1; s < 64; s <<= 1) l += __shfl_xor(l, s);

    if (lane == 0) {
        float* o = out + row * DH;
        o[0] = m;
        o[1] = l;
    }
}

// ================= Pass 2: out = exp(x1 - m)/l @ x2^T ============================
// One wave = 16 q-rows, full Dh=64 (4 n-tiles of 16). Stats precomputed -> no
// cross-lane ops, no acc rescale, no loop-carried dep except acc. x1 register
// prefetch depth 2 (load window = 2 iterations). x2 double-buffered in LDS fp16.
// A-frag (16x16x32): A[m=lane&15][k=quad*8+j];  B[k][n=lane&15] = x2[n][k]
// C/D: n=lane&15, m=quad*4+reg (verified layouts, m89/m91/m120)
extern "C" __global__ __launch_bounds__(256, 4)
void softmax_matmul_f16(const float* __restrict__ x1,
                        const float* __restrict__ x2,
                        float* __restrict__ out)
{
    __shared__ _Float16 ldsb[2][BM * PITCH];    // 2 x 9216 B = 18.4 KB

    const int tid  = threadIdx.x;
    const int wave = tid >> 6;
    const int lane = tid & 63;
    const int r    = lane & 15;
    const int quad = lane >> 4;

    const int bh   = blockIdx.x >> 5;          // SEQ/BM = 32 q-blocks per bh
    const int qblk = blockIdx.x & 31;
    const int row0 = qblk * BM + wave * 16;

    const size_t rbase_g = (size_t)bh * SEQ + (size_t)row0;
    const float* x1row = x1 + (rbase_g + r) * SEQ;
    const float* x2bh  = x2 + (size_t)bh * DH * SEQ;       // [64][2048]
    float*       obase = out + rbase_g * DH;

    // ---- stats: read BEFORE any store into out (all reads up-front, no race)
    const float sh = out[(rbase_g + r) * DH] * LOG2E;      // shift for own q-row
    float rlr[4];
#pragma unroll
    for (int g = 0; g < 4; ++g)
        rlr[g] = 1.0f / out[(rbase_g + quad * 4 + g) * DH + 1];  // 1/l for C-rows

    // block-wide x2 staging role: thread -> (row sr, 16-float col group sc)
    const int sr = tid >> 2;
    const int sc = (tid & 3) * 16;
    const float* x2st = x2bh + (size_t)sr * SEQ + sc;
    _Float16* const ldsw0 = &ldsb[0][sr * PITCH + sc];
    _Float16* const ldsw1 = &ldsb[1][sr * PITCH + sc];

    f32x4 acc[4];
#pragma unroll
    for (int t = 0; t < 4; ++t) acc[t] = (f32x4){0.f, 0.f, 0.f, 0.f};

    // ---- prologue: stage x2 chunk 0 -> buf0 (coalesced 64B/thread)
    {
        float4 s0 = *(const float4*)(x2st + 0);
        float4 s1 = *(const float4*)(x2st + 4);
        float4 s2 = *(const float4*)(x2st + 8);
        float4 s3 = *(const float4*)(x2st + 12);
        f16x8 h0, h1;
        h0[0] = (_Float16)s0.x; h0[1] = (_Float16)s0.y; h0[2] = (_Float16)s0.z; h0[3] = (_Float16)s0.w;
        h0[4] = (_Float16)s1.x; h0[5] = (_Float16)s1.y; h0[6] = (_Float16)s1.z; h0[7] = (_Float16)s1.w;
        h1[0] = (_Float16)s2.x; h1[1] = (_Float16)s2.y; h1[2] = (_Float16)s2.z; h1[3] = (_Float16)s2.w;
        h1[4] = (_Float16)s3.x; h1[5] = (_Float16)s3.y; h1[6] = (_Float16)s3.z; h1[7] = (_Float16)s3.w;
        *(f16x8*)(ldsw0 + 0) = h0;
        *(f16x8*)(ldsw0 + 8) = h1;
    }

    // ---- prologue: x1 prefetch depth 2 (chunk 0 -> A*, chunk 1 -> B*)
    const float* pf = x1row + quad * 8;
    float4 A0 = *(const float4*)(pf + 0);
    float4 A1 = *(const float4*)(pf + 4);
    float4 A2 = *(const float4*)(pf + 32);
    float4 A3 = *(const float4*)(pf + 36);
    pf = x1row + BK + quad * 8;
    float4 B0 = *(const float4*)(pf + 0);
    float4 B1 = *(const float4*)(pf + 4);
    float4 B2 = *(const float4*)(pf + 32);
    float4 B3 = *(const float4*)(pf + 36);

    __syncthreads();

    auto step = [&](int k0, const _Float16* __restrict__ rdbase,
                    _Float16* __restrict__ wptr,
                    float4& c0, float4& c1, float4& c2, float4& c3) {
        // consume current x1 regs straight into fp16 A-frags (no p[] array)
        f16x8 ah0, ah1;
        ah0[0] = (_Float16)__builtin_amdgcn_exp2f(__builtin_fmaf(c0.x, LOG2E, -sh));
        ah0[1] = (_Float16)__builtin_amdgcn_exp2f(__builtin_fmaf(c0.y, LOG2E, -sh));
        ah0[2] = (_Float16)__builtin_amdgcn_exp2f(__builtin_fmaf(c0.z, LOG2E, -sh));
        ah0[3] = (_Float16)__builtin_amdgcn_exp2f(__builtin_fmaf(c0.w, LOG2E, -sh));
        ah0[4] = (_Float16)__builtin_amdgcn_exp2f(__builtin_fmaf(c1.x, LOG2E, -sh));
        ah0[5] = (_Float16)__builtin_amdgcn_exp2f(__builtin_fmaf(c1.y, LOG2E, -sh));
        ah0[6] = (_Float16)__builtin_amdgcn_exp2f(__builtin_fmaf(c1.z, LOG2E, -sh));
        ah0[7] = (_Float16)__builtin_amdgcn_exp2f(__builtin_fmaf(c1.w, LOG2E, -sh));
        ah1[0] = (_Float16)__builtin_amdgcn_exp2f(__builtin_fmaf(c2.x, LOG2E, -sh));
        ah1[1] = (_Float16)__builtin_amdgcn_exp2f(__builtin_fmaf(c2.y, LOG2E, -sh));
        ah1[2] = (_Float16)__builtin_amdgcn_exp2f(__builtin_fmaf(c2.z, LOG2E, -sh));
        ah1[3] = (_Float16)__builtin_amdgcn_exp2f(__builtin_fmaf(c2.w, LOG2E, -sh));
        ah1[4] = (_Float16)__builtin_amdgcn_exp2f(__builtin_fmaf(c3.x, LOG2E, -sh));
        ah1[5] = (_Float16)__builtin_amdgcn_exp2f(__builtin_fmaf(c3.y, LOG2E, -sh));
        ah1[6] = (_Float16)__builtin_amdgcn_exp2f(__builtin_fmaf(c3.z, LOG2E, -sh));
        ah1[7] = (_Float16)__builtin_amdgcn_exp2f(__builtin_fmaf(c3.w, LOG2E, -sh));

        // issue x1 prefetch for k0+128 into the now-dead regs (2-iteration window)
        const int kpf = k0 + 2 * BK;
        if (kpf < SEQ) {
            const float* pn = x1row + kpf + quad * 8;
            c0 = *(const float4*)(pn + 0);
            c1 = *(const float4*)(pn + 4);
            c2 = *(const float4*)(pn + 32);
            c3 = *(const float4*)(pn + 36);
        }

        // issue x2 stage loads for next chunk (written to LDS after MFMAs)
        const int k1 = k0 + BK;
        float4 s0, s1, s2, s3;
        if (k1 < SEQ) {
            const float* ps = x2st + k1;
            s0 = *(const float4*)(ps + 0);
            s1 = *(const float4*)(ps + 4);
            s2 = *(const float4*)(ps + 8);
            s3 = *(const float4*)(ps + 12);
        }

        // B frags from LDS fp16 (ds_read_b128, 2-way banks = free) + MFMA
#pragma unroll
        for (int t = 0; t < 4; ++t) {
            const _Float16* bp = rdbase + (t * 16 + r) * PITCH + quad * 8;
            f16x8 bf0 = *(const f16x8*)(bp);
            f16x8 bf1 = *(const f16x8*)(bp + 32);
            acc[t] = __builtin_amdgcn_mfma_f32_16x16x32_f16(ah0, bf0, acc[t], 0, 0, 0);
            acc[t] = __builtin_amdgcn_mfma_f32_16x16x32_f16(ah1, bf1, acc[t], 0, 0, 0);
        }

        // write next x2 chunk to the other buffer, then barrier
        if (k1 < SEQ) {
            f16x8 h0, h1;
            h0[0] = (_Float16)s0.x; h0[1] = (_Float16)s0.y; h0[2] = (_Float16)s0.z; h0[3] = (_Float16)s0.w;
            h0[4] = (_Float16)s1.x; h0[5] = (_Float16)s1.y; h0[6] = (_Float16)s1.z; h0[7] = (_Float16)s1.w;
            h1[0] = (_Float16)s2.x; h1[1] = (_Float16)s2.y; h1[2] = (_Float16)s2.z; h1[3] = (_Float16)s2.w;
            h1[4] = (_Float16)s3.x; h1[5] = (_Float16)s3.y; h1[6] = (_Float16)s3.z; h1[7] = (_Float16)s3.w;
            *(f16x8*)(wptr + 0) = h0;
            *(f16x8*)(wptr + 8) = h1;
        }
        __syncthreads();
    };

    // 2x-unrolled: compile-time buffer + register-set selection (rule #20)
#pragma unroll 1
    for (int k0 = 0; k0 < SEQ; k0 += 2 * BK) {
        step(k0,      &ldsb[0][0], ldsw1, A0, A1, A2, A3);
        step(k0 + BK, &ldsb[1][0], ldsw0, B0, B1, B2, B3);
    }

    // ---- epilogue: C rows quad*4+g, col t*16+r, scaled by 1/l
#pragma unroll
    for (int t = 0; t < 4; ++t)
#pragma unroll
        for (int g = 0; g < 4; ++g)
            obase[(size_t)(quad * 4 + g) * DH + t * 16 + r] = acc[t][g] * rlr[g];
}

extern "C" void kernel_launch(void* const* d_in, const int* in_sizes, int n_in,
                              void* d_out, int out_size, void* d_ws, size_t ws_size,
                              hipStream_t stream)
{
    const float* x1 = (const float*)d_in[0];
    const float* x2 = (const float*)d_in[1];
    float* out = (float*)d_out;

    const int bhCount = in_sizes[1] / (DH * SEQ);   // B*H = 32 (same as verified)
    dim3 block(256);

    dim3 g1(bhCount * SEQ / 4);                     // 1 row/wave, 4 waves/block
    hipLaunchKernelGGL(softmax_stats, g1, block, 0, stream, x1, out);

    dim3 g2(bhCount * (SEQ / BM));                  // 1024 blocks
    hipLaunchKernelGGL(softmax_matmul_f16, g2, block, 0, stream, x1, x2, out);
}